// Round 3
// baseline (8348.709 us; speedup 1.0000x reference)
//
#include <hip/hip_runtime.h>
#include <hip/hip_bf16.h>

// Problem constants (HAGCNBlock): x (N,C,T,V) fp32
#define NN 32
#define CC 256
#define TT 256
#define VV 27
#define VP 32      // padded V for LDS tiles
#define KK 3
#define F_EPS 1e-5f

// Workspace layout (in floats), packed tight — total 57,442,304 f = 229.8 MB:
//   [0      , 2592  )  Ac[k][v][w]  (w padded to VP, pads = 0)
//   [4096   , 12288 )  Bb[o][w]     (bias from bg through A_comb; w padded VP)
//   [16384  , 16640 )  s1[c]   = g1_gamma*rsqrt(g1_var+eps)
//   [16640  , 16896 )  b1[c]   = g1_beta - g1_mean*s1
//   [16896  , 17152 )  s2[c]   = g2_gamma*rsqrt(g2_var+eps)
//   [17152  , 17408 )  sh2[c]  = (bt - g2_mean)*s2 + g2_beta
//   [32768  , 229376)  WgT[kc][o]   kc = k*C + c  (768 x 256)
//   [229376 , 819200)  WtT[(c*9+dt)][o]  (2304 x 256) — lane-coalesced weights
//   [819200 , 57442304) y1[n][c][t][v]  (N*C*T*V floats)
#define WS_AC    0
#define WS_BB    4096
#define WS_S1    16384
#define WS_B1    16640
#define WS_S2    16896
#define WS_SH2   17152
#define WS_WGT   32768
#define WS_WTT   229376
#define WS_Y1    819200

// ---------------------------------------------------------------- precompute
__global__ void k_pre(const float* __restrict__ A, const float* __restrict__ SH,
                      const float* __restrict__ PH, const float* __restrict__ PA,
                      const float* __restrict__ alpha, const float* __restrict__ beta,
                      const float* __restrict__ bg,
                      const float* __restrict__ g1g, const float* __restrict__ g1b,
                      const float* __restrict__ g1m, const float* __restrict__ g1v,
                      const float* __restrict__ bt,
                      const float* __restrict__ g2g, const float* __restrict__ g2b,
                      const float* __restrict__ g2m, const float* __restrict__ g2v,
                      float* __restrict__ ws) {
    __shared__ float cs[KK * VP];   // column sums of A_comb
    const int tid = threadIdx.x;
    float* Ac  = ws + WS_AC;
    float* Bb  = ws + WS_BB;
    float* s1  = ws + WS_S1;
    float* b1  = ws + WS_B1;
    float* s2  = ws + WS_S2;
    float* sh2 = ws + WS_SH2;

    const float al = alpha[0], be = beta[0];
    for (int i = tid; i < KK * VV * VP; i += 256) {
        const int k = i / (VV * VP);
        const int r = i - k * (VV * VP);
        const int v = r / VP;
        const int w = r - v * VP;
        float val = 0.0f;
        if (w < VV) {
            const int src = (k * VV + v) * VV + w;
            val = A[src] + PA[src] + SH[src] * al + PH[src] * be;
        }
        Ac[i] = val;
    }
    __syncthreads();
    if (tid < KK * VP) {
        const int k = tid / VP;
        const int w = tid - k * VP;
        float s = 0.0f;
        for (int v = 0; v < VV; ++v) s += Ac[(k * VV + v) * VP + w];
        cs[tid] = s;
    }
    __syncthreads();
    for (int i = tid; i < CC * VP; i += 256) {
        const int o = i / VP;
        const int w = i - o * VP;
        float s = 0.0f;
        for (int k = 0; k < KK; ++k) s += bg[k * CC + o] * cs[k * VP + w];
        Bb[i] = s;
    }
    if (tid < CC) {
        const float s1v = g1g[tid] * rsqrtf(g1v[tid] + F_EPS);
        s1[tid] = s1v;
        b1[tid] = g1b[tid] - g1m[tid] * s1v;
        const float s2v = g2g[tid] * rsqrtf(g2v[tid] + F_EPS);
        s2[tid] = s2v;
        sh2[tid] = (bt[tid] - g2m[tid]) * s2v + g2b[tid];
    }
}

// Transpose Wg (K,O,C) -> WgT[(k*C+c)][o]
__global__ void k_wgt(const float* __restrict__ Wg, float* __restrict__ WgT) {
    const int kc = blockIdx.x;              // 0..767
    const int k = kc >> 8;
    const int c = kc & 255;
    const int o = threadIdx.x;
    WgT[kc * CC + o] = Wg[(k * CC + o) * CC + c];
}

// Transpose Wt (O,C,9,1) -> WtT[(c*9+dt)][o]  (lane-coalesced in o)
__global__ void k_wtt(const float* __restrict__ Wt, float* __restrict__ WtT) {
    const int cd = blockIdx.x;              // 0..2303 = c*9+dt
    const int c  = cd / 9;
    const int dt = cd - c * 9;
    const int o  = threadIdx.x;
    WtT[cd * CC + o] = Wt[(o * CC + c) * 9 + dt];
}

// ---------------------------------------------------------------- GCN (fused z + GEMM + BN1 + relu + residual)
// block = one (n,t); 512 threads.
// y1[n,o,t,w] = relu( (sum_kc WgT[kc][o]*z[kc][w] + Bb[o][w])*s1[o] + b1[o] + x[n,o,t,w] )
// z[kc][w] = sum_v x[n,c,t,v]*Ac[k][v][w]
__global__ __launch_bounds__(512, 2) void k_gcn(const float* __restrict__ x,
                                                const float* __restrict__ ws,
                                                float* __restrict__ y1) {
    __shared__ __align__(16) float xs[CC * VV];      // 6912 f  (27.0 KB)
    __shared__ __align__(16) float Acs[KK * VV * VP];// 2592 f  (10.1 KB)
    __shared__ __align__(16) float zc[64 * VP];      // 2048 f  ( 8.0 KB)
    __shared__ __align__(16) float wgs[16 * CC];     // 4096 f  (16.0 KB)

    const int tid = threadIdx.x;
    const int b   = blockIdx.x;
    const int n   = b >> 8;
    const int t   = b & 255;

    const float* xbase = x + (n * CC * TT + t) * VV;   // + c*(T*V) + v
    for (int i = tid; i < CC * VV; i += 512) {
        const int c = i / VV;
        const int v = i - c * VV;
        xs[i] = xbase[c * (TT * VV) + v];
    }
    for (int i = tid; i < KK * VV * VP; i += 512) Acs[i] = ws[WS_AC + i];
    __syncthreads();

    const int og = tid & 127;      // o pair index
    const int wg = tid >> 7;       // 0..3 -> 8 w's each
    const int o0 = og * 2;
    const int w0 = wg * 8;
    const int zcl = tid >> 3;      // 0..63 (c within chunk)
    const int zw4 = (tid & 7) * 4; // w4 group

    float acc[2][8];
#pragma unroll
    for (int j = 0; j < 2; ++j)
#pragma unroll
        for (int wi = 0; wi < 8; ++wi) acc[j][wi] = 0.0f;

    const float* WgT = ws + WS_WGT;

#pragma unroll 1
    for (int kc0 = 0; kc0 < KK * CC; kc0 += 64) {
        const int k  = kc0 >> 8;
        const int cb = kc0 & 255;
        // ---- compute this thread's z chunk values in registers
        float sx = 0.f, sy = 0.f, sz = 0.f, sw = 0.f;
        {
            const float* xr = &xs[(cb + zcl) * VV];
            const float* ar = &Acs[k * (VV * VP) + zw4];
#pragma unroll
            for (int v = 0; v < VV; ++v) {
                const float xv = xr[v];
                const float4 a = *(const float4*)(ar + v * VP);
                sx = fmaf(xv, a.x, sx);
                sy = fmaf(xv, a.y, sy);
                sz = fmaf(xv, a.z, sz);
                sw = fmaf(xv, a.w, sw);
            }
        }
        __syncthreads();   // previous chunk's GEMM finished reading zc/wgs
        {
            float4 zv; zv.x = sx; zv.y = sy; zv.z = sz; zv.w = sw;
            *(float4*)&zc[zcl * VP + zw4] = zv;
        }
#pragma unroll 1
        for (int st = 0; st < 4; ++st) {
            if (st > 0) __syncthreads();   // previous stage GEMM done reading wgs
            {   // stage 16 rows of WgT into LDS (4096 floats)
                const int rowbase = (kc0 + st * 16) * CC;
                *(float4*)&wgs[tid * 4]         = *(const float4*)&WgT[rowbase + tid * 4];
                *(float4*)&wgs[(tid + 512) * 4] = *(const float4*)&WgT[rowbase + (tid + 512) * 4];
            }
            __syncthreads();               // wgs (and zc on st==0) visible
            const int klb = st * 16;
#pragma unroll
            for (int kci = 0; kci < 16; ++kci) {
                const float2 wv = *(const float2*)&wgs[kci * CC + o0];
                const float4 z0 = *(const float4*)&zc[(klb + kci) * VP + w0];
                const float4 z1 = *(const float4*)&zc[(klb + kci) * VP + w0 + 4];
                const float zr[8] = {z0.x, z0.y, z0.z, z0.w, z1.x, z1.y, z1.z, z1.w};
#pragma unroll
                for (int wi = 0; wi < 8; ++wi) {
                    acc[0][wi] = fmaf(wv.x, zr[wi], acc[0][wi]);
                    acc[1][wi] = fmaf(wv.y, zr[wi], acc[1][wi]);
                }
            }
        }
    }

    // ---- epilogue: bias, BN1, residual, relu -> y1
    const float* s1p = ws + WS_S1;
    const float* b1p = ws + WS_B1;
    const float* Bb  = ws + WS_BB;
    float* ybase = y1 + (n * CC * TT + t) * VV;   // + o*(T*V) + w
#pragma unroll
    for (int j = 0; j < 2; ++j) {
        const int o = o0 + j;
        const float s = s1p[o];
        const float bb = b1p[o];
#pragma unroll
        for (int wi = 0; wi < 8; ++wi) {
            const int w = w0 + wi;
            if (w < VV) {
                const float pre = acc[j][wi] + Bb[o * VP + w];
                const float val = fmaf(pre, s, bb) + xs[o * VV + w];
                ybase[o * (TT * VV) + w] = fmaxf(val, 0.0f);
            }
        }
    }
}

// ---------------------------------------------------------------- temporal conv (9,1) + bt + BN2 + residual + relu
// block = (n, t-tile of 4); 512 threads: thread = (o = tid&255, vhalf = tid>>8)
// Within a wave, all lanes share the same ys row pointer -> broadcast LDS reads.
__global__ __launch_bounds__(512, 2) void k_tconv(const float* __restrict__ y1,
                                                  const float* __restrict__ x,
                                                  const float* __restrict__ WtT,
                                                  const float* __restrict__ ws,
                                                  float* __restrict__ out) {
    __shared__ __align__(16) float ys[32 * 12 * VP];   // 12288 f (48 KB)
    const int tid = threadIdx.x;
    const int b   = blockIdx.x;
    const int n   = b >> 6;            // T/4 = 64 tiles
    const int t0  = (b & 63) * 4;
    const int o   = tid & 255;
    const int vh  = tid >> 8;
    const int v0  = vh * 16;

    // zero the v-pads once (they are never re-written by staging)
    for (int i = tid; i < 32 * 12 * (VP - VV); i += 512) {
        const int cl = i / (12 * (VP - VV));
        const int r  = i - cl * (12 * (VP - VV));
        const int tt = r / (VP - VV);
        const int v  = VV + (r - tt * (VP - VV));
        ys[(cl * 12 + tt) * VP + v] = 0.0f;
    }

    float acc[4][16];
#pragma unroll
    for (int tt = 0; tt < 4; ++tt)
#pragma unroll
        for (int vi = 0; vi < 16; ++vi) acc[tt][vi] = 0.0f;

#pragma unroll 1
    for (int c0 = 0; c0 < CC; c0 += 32) {
        __syncthreads();   // prior compute done reading ys (covers pad-zeroing on first iter)
        // stage y1[n, c0..c0+31, t0-4 .. t0+7, :] with zero padding at T edges
        for (int i = tid; i < 32 * 12 * VV; i += 512) {
            const int cl = i / (12 * VV);
            const int r  = i - cl * (12 * VV);
            const int tt = r / VV;
            const int v  = r - tt * VV;
            const int t  = t0 - 4 + tt;
            float val = 0.0f;
            if (t >= 0 && t < TT) val = y1[((n * CC + c0 + cl) * TT + t) * VV + v];
            ys[(cl * 12 + tt) * VP + v] = val;
        }
        __syncthreads();
#pragma unroll 1
        for (int cl = 0; cl < 32; ++cl) {
            float wt[9];
            const float* wp = WtT + (c0 + cl) * 9 * CC + o;   // lane-coalesced
#pragma unroll
            for (int dt = 0; dt < 9; ++dt) wt[dt] = wp[dt * CC];
            const float* yrow = &ys[cl * 12 * VP + v0];
#pragma unroll
            for (int tau = 0; tau < 12; ++tau) {
                const float4 r0 = *(const float4*)(yrow + tau * VP);
                const float4 r1 = *(const float4*)(yrow + tau * VP + 4);
                const float4 r2 = *(const float4*)(yrow + tau * VP + 8);
                const float4 r3 = *(const float4*)(yrow + tau * VP + 12);
                const float rr[16] = {r0.x, r0.y, r0.z, r0.w, r1.x, r1.y, r1.z, r1.w,
                                      r2.x, r2.y, r2.z, r2.w, r3.x, r3.y, r3.z, r3.w};
#pragma unroll
                for (int tt = 0; tt < 4; ++tt) {
                    const int dt = tau - tt;
                    if (dt >= 0 && dt < 9) {
                        const float w = wt[dt];
#pragma unroll
                        for (int vi = 0; vi < 16; ++vi)
                            acc[tt][vi] = fmaf(w, rr[vi], acc[tt][vi]);
                    }
                }
            }
        }
    }

    // epilogue: BN2 (bt folded) + residual + relu
    const float s2o  = ws[WS_S2 + o];
    const float sh2o = ws[WS_SH2 + o];
#pragma unroll
    for (int tt = 0; tt < 4; ++tt) {
        const int t = t0 + tt;
        const float* xr = x + ((n * CC + o) * TT + t) * VV;
        float* op = out + ((n * CC + o) * TT + t) * VV;
#pragma unroll
        for (int vi = 0; vi < 16; ++vi) {
            const int v = v0 + vi;
            if (v < VV) {
                const float val = fmaf(acc[tt][vi], s2o, sh2o) + xr[v];
                op[v] = fmaxf(val, 0.0f);
            }
        }
    }
}

// ---------------------------------------------------------------- launch
extern "C" void kernel_launch(void* const* d_in, const int* in_sizes, int n_in,
                              void* d_out, int out_size, void* d_ws, size_t ws_size,
                              hipStream_t stream) {
    (void)in_sizes; (void)n_in; (void)out_size; (void)ws_size;
    const float* x     = (const float*)d_in[0];
    const float* A     = (const float*)d_in[1];
    const float* SH    = (const float*)d_in[2];
    const float* PH    = (const float*)d_in[3];
    const float* PA    = (const float*)d_in[4];
    const float* alpha = (const float*)d_in[5];
    const float* beta  = (const float*)d_in[6];
    const float* Wg    = (const float*)d_in[7];
    const float* bg    = (const float*)d_in[8];
    const float* g1g   = (const float*)d_in[9];
    const float* g1b   = (const float*)d_in[10];
    const float* g1m   = (const float*)d_in[11];
    const float* g1v   = (const float*)d_in[12];
    const float* Wt    = (const float*)d_in[13];
    const float* bt    = (const float*)d_in[14];
    const float* g2g   = (const float*)d_in[15];
    const float* g2b   = (const float*)d_in[16];
    const float* g2m   = (const float*)d_in[17];
    const float* g2v   = (const float*)d_in[18];

    float* ws  = (float*)d_ws;
    float* out = (float*)d_out;
    float* y1  = ws + WS_Y1;
    float* WgT = ws + WS_WGT;
    float* WtT = ws + WS_WTT;

    hipLaunchKernelGGL(k_pre, dim3(1), dim3(256), 0, stream,
                       A, SH, PH, PA, alpha, beta, bg,
                       g1g, g1b, g1m, g1v, bt, g2g, g2b, g2m, g2v, ws);
    hipLaunchKernelGGL(k_wgt, dim3(KK * CC), dim3(CC), 0, stream, Wg, WgT);
    hipLaunchKernelGGL(k_wtt, dim3(CC * 9), dim3(CC), 0, stream, Wt, WtT);
    hipLaunchKernelGGL(k_gcn, dim3(NN * TT), dim3(512), 0, stream, x, ws, y1);
    hipLaunchKernelGGL(k_tconv, dim3(NN * (TT / 4)), dim3(512), 0, stream, y1, x, WtT, ws, out);
}